// Round 13
// baseline (8297.301 us; speedup 1.0000x reference)
//
#include <hip/hip_runtime.h>
#include <cstdint>
#include <cstddef>

#define T_ 512
#define B_ 32
#define D_ 1024
#define L_ 4
#define BD_ (B_*D_)
#define TPB 256
#define NWG 256
#define EPSF 1e-5f

typedef _Float16 f16x8 __attribute__((ext_vector_type(8)));
typedef float f32x4 __attribute__((ext_vector_type(4)));
typedef float f32x2 __attribute__((ext_vector_type(2)));
typedef unsigned int u32x4 __attribute__((ext_vector_type(4)));
typedef unsigned int u32x2 __attribute__((ext_vector_type(2)));
typedef unsigned long long u64;

// workspace layout (bytes) — no-reuse streams (r12)
#define WSO_PROG   0
#define WSO_XSTAT  4096
#define WSO_HSTAT  135168
#define WSO_YSTAT  528384
#define WSO_ZEND   659456
#define WSO_WT     1048576
#define WSO_H16    34603008

// LDS layout (bytes)
#define LDS_W     0
#define LDS_DUMP  131072
#define LDS_GB    147456
#define LDS_NS    155904
#define LDS_BIAS  158464
#define LDS_SGSB  158592
#define LDS_TOTAL 158720
#define NSTR 20

__device__ __forceinline__ unsigned pk2h(float a, float b){
  _Float16 ha=(_Float16)a, hb=(_Float16)b;
  return (unsigned)__builtin_bit_cast(unsigned short,ha) |
         ((unsigned)__builtin_bit_cast(unsigned short,hb)<<16);
}
__device__ __forceinline__ float cload1(const float* p){
  unsigned v=__hip_atomic_load((const unsigned*)(const void*)p,__ATOMIC_RELAXED,__HIP_MEMORY_SCOPE_AGENT);
  return __builtin_bit_cast(float,v);
}
__device__ __forceinline__ unsigned cldu(const unsigned* p){
  return __hip_atomic_load(p,__ATOMIC_RELAXED,__HIP_MEMORY_SCOPE_AGENT);
}
__device__ __forceinline__ void cstore16(unsigned short* p, unsigned w0, unsigned w1, unsigned w2, unsigned w3){
  u64 lo=((u64)w1<<32)|w0, hi=((u64)w3<<32)|w2;
  __hip_atomic_store((u64*)(void*)p,     lo, __ATOMIC_RELAXED, __HIP_MEMORY_SCOPE_AGENT);
  __hip_atomic_store((u64*)(void*)(p+4), hi, __ATOMIC_RELAXED, __HIP_MEMORY_SCOPE_AGENT);
}

#define GLDX(d,vo,sb)  asm volatile("global_load_dwordx4 %0, %1, %2" : "=v"(d) : "v"(vo), "s"(sb) : "memory")
#define GLDX2(d,vo,sb) asm volatile("global_load_dwordx2 %0, %1, %2" : "=v"(d) : "v"(vo), "s"(sb) : "memory")
#define WAITV(N) do{ asm volatile("s_waitcnt vmcnt(" #N ")" ::: "memory"); __builtin_amdgcn_sched_barrier(0); }while(0)
#define BARS do{ asm volatile("s_waitcnt lgkmcnt(0)" ::: "memory"); __builtin_amdgcn_s_barrier(); }while(0)

// 4 MFMAs against LDS-resident weights for fused-k chunk cc
#define MM(cc) do{ \
    const int kb_=(((cc)*128+kq))*2; \
    f16x8 bF=*(const f16x8*)(WF + (kb_^swl)); \
    f16x8 bC=*(const f16x8*)(WC + (kb_^swl)); \
    accF0=__builtin_amdgcn_mfma_f32_16x16x32_f16(a0,bF,accF0,0,0,0); \
    accF1=__builtin_amdgcn_mfma_f32_16x16x32_f16(a1,bF,accF1,0,0,0); \
    accC0=__builtin_amdgcn_mfma_f32_16x16x32_f16(a0,bC,accC0,0,0,0); \
    accC1=__builtin_amdgcn_mfma_f32_16x16x32_f16(a1,bC,accC1,0,0,0); \
  }while(0)

// state chunk i (global chunk 8+i): raw fp16
#define PSI(i,NW) do{ WAITV(NW); \
    f16x8 a0=__builtin_bit_cast(f16x8,pS[2*(i)]); \
    f16x8 a1=__builtin_bit_cast(f16x8,pS[2*(i)+1]); \
    MM(8+(i)); }while(0)

// h chunk c, fp16 input + packed-fp16 LN (li>0)
#define PHN(c,NW) do{ WAITV(NW); \
    f16x8 a0=__builtin_bit_cast(f16x8,pH[2*(c)]); \
    f16x8 a1=__builtin_bit_cast(f16x8,pH[2*(c)+1]); \
    const int kf_=(c)*128+kq; \
    f16x8 g8=*(const f16x8*)(GBg16+(kf_>>1)); \
    f16x8 b8=*(const f16x8*)(GBg16+512+(kf_>>1)); \
    a0=a0*rsA8+nmA8; a0=a0*g8+b8; \
    a1=a1*rsB8+nmB8; a1=a1*g8+b8; \
    MM(c); }while(0)

// x chunk c, fp32 input + f32 LN (li==0)
#define PHX(c,NW) do{ WAITV(NW); \
    f32x4 xa0=__builtin_bit_cast(f32x4,pX[4*(c)]),   xa1=__builtin_bit_cast(f32x4,pX[4*(c)+1]); \
    f32x4 xb0=__builtin_bit_cast(f32x4,pX[4*(c)+2]), xb1=__builtin_bit_cast(f32x4,pX[4*(c)+3]); \
    const int kf_=(c)*128+kq; \
    f32x4 g0=*(const f32x4*)(GBg32+kf_), g1=*(const f32x4*)(GBg32+kf_+4); \
    f32x4 q0=*(const f32x4*)(GBg32+1024+kf_), q1=*(const f32x4*)(GBg32+1024+kf_+4); \
    f16x8 a0,a1; \
    a0[0]=(_Float16)((xa0[0]*rsA+nmA)*g0[0]+q0[0]); a0[1]=(_Float16)((xa0[1]*rsA+nmA)*g0[1]+q0[1]); \
    a0[2]=(_Float16)((xa0[2]*rsA+nmA)*g0[2]+q0[2]); a0[3]=(_Float16)((xa0[3]*rsA+nmA)*g0[3]+q0[3]); \
    a0[4]=(_Float16)((xa1[0]*rsA+nmA)*g1[0]+q1[0]); a0[5]=(_Float16)((xa1[1]*rsA+nmA)*g1[1]+q1[1]); \
    a0[6]=(_Float16)((xa1[2]*rsA+nmA)*g1[2]+q1[2]); a0[7]=(_Float16)((xa1[3]*rsA+nmA)*g1[3]+q1[3]); \
    a1[0]=(_Float16)((xb0[0]*rsB+nmB)*g0[0]+q0[0]); a1[1]=(_Float16)((xb0[1]*rsB+nmB)*g0[1]+q0[1]); \
    a1[2]=(_Float16)((xb0[2]*rsB+nmB)*g0[2]+q0[2]); a1[3]=(_Float16)((xb0[3]*rsB+nmB)*g0[3]+q0[3]); \
    a1[4]=(_Float16)((xb1[0]*rsB+nmB)*g1[0]+q1[0]); a1[5]=(_Float16)((xb1[1]*rsB+nmB)*g1[1]+q1[1]); \
    a1[6]=(_Float16)((xb1[2]*rsB+nmB)*g1[2]+q1[2]); a1[7]=(_Float16)((xb1[3]*rsB+nmB)*g1[3]+q1[3]); \
    MM(c); }while(0)

// ---------------- pre-pass 1 ----------------
extern "C" __global__ void __launch_bounds__(256,1) crs_prepass(
    const float* __restrict__ Wf, const float* __restrict__ Uf,
    const float* __restrict__ Wc, const float* __restrict__ Uc,
    unsigned short* __restrict__ WT)
{
  int bid = blockIdx.x;
  int kt  = bid & 15;
  int ct  = (bid>>4) & 31;
  int sel = (bid>>9) & 3;
  int i   = bid >> 11;
  int tid = threadIdx.x;
  int kq  = tid >> 5;
  int cc  = tid & 31;
  const float* sp;
  if      (sel==0) sp = Wf;
  else if (sel==1) sp = Uf;
  else if (sel==2) sp = Wc;
  else             sp = Uc;
  sp += (size_t)i * 1048576;
  int cl = ct*32 + cc;
  int k0 = kt*64 + kq*8;
  float f[8];
  #pragma unroll
  for (int e=0;e<8;++e){ f[e] = sp[(size_t)(k0+e)*1024 + cl]; }
  int cg = ((sel>>1) ? 1024 : 0) + cl;
  int ks = sel & 1;
  size_t idx = ((size_t)(i*2048 + cg)*2 + ks)*1024 + k0;
  uint4 pk;
  pk.x = pk2h(f[0], f[1]);
  pk.y = pk2h(f[2], f[3]);
  pk.z = pk2h(f[4], f[5]);
  pk.w = pk2h(f[6], f[7]);
  *(uint4*)(WT + idx) = pk;
}

// ---------------- pre-pass 2 ----------------
extern "C" __global__ void __launch_bounds__(256,1) crs_prep2(
    const float* __restrict__ x, const float* __restrict__ st0,
    float* __restrict__ xstat, unsigned short* __restrict__ H16)
{
  __shared__ float2 part[256];
  int bid=blockIdx.x, tid=threadIdx.x;
  int rr=tid>>3, ss=tid&7;
  if (bid<T_){
    const float4* p4=(const float4*)(x+(size_t)bid*BD_+rr*1024+ss*128);
    float s1=0.f,s2=0.f;
    #pragma unroll 8
    for (int q=0;q<32;++q){ float4 a=p4[q]; s1+=a.x+a.y+a.z+a.w; s2+=a.x*a.x+a.y*a.y+a.z*a.z+a.w*a.w; }
    part[tid]=make_float2(s1,s2);
    __syncthreads();
    if (tid<32){
      float a1=0.f,a2=0.f;
      #pragma unroll
      for (int e=0;e<8;++e){ float2 pp=part[tid*8+e]; a1+=pp.x; a2+=pp.y; }
      xstat[bid*64+tid*2]=a1; xstat[bid*64+tid*2+1]=a2;
    }
  } else {
    int i2=bid-T_;
    const float4* p4=(const float4*)(st0+(size_t)i2*BD_+rr*1024+ss*128);
    uint4* dst=(uint4*)(H16+(size_t)i2*513*32768+rr*1024+ss*128);
    #pragma unroll
    for (int q=0;q<16;++q){
      float4 a=p4[2*q], b=p4[2*q+1];
      uint4 pk; pk.x=pk2h(a.x,a.y); pk.y=pk2h(a.z,a.w); pk.z=pk2h(b.x,b.y); pk.w=pk2h(b.z,b.w);
      dst[q]=pk;
    }
  }
}

// ---------------- main persistent kernel ----------------
extern "C" __global__ void __launch_bounds__(TPB,1) crs_main(
    const float* __restrict__ x, const float* __restrict__ st0,
    const float* __restrict__ bfv, const float* __restrict__ bcv,
    const float* __restrict__ pg, const float* __restrict__ pb,
    const float* __restrict__ sg, const float* __restrict__ sbv,
    float* __restrict__ y, float* __restrict__ ostate,
    const unsigned short* __restrict__ WT, char* __restrict__ ws)
{
  extern __shared__ char smem[];
  const int tid=threadIdx.x, w=blockIdx.x;
  const int li=w>>6, wr=w&63;
  const int lane=tid&63, v=tid>>6;
  const int l15=lane&15, lg=(lane>>4)&3;
  const int kq = v*32 + lg*8;
  const int col=lane&15, rp=lane>>4;
  const int r0=v*8+rp, r1=v*8+4+rp;
  const int sseg=tid&7;

  unsigned* prog=(unsigned*)(ws+WSO_PROG);
  float* hstat=(float*)(ws+WSO_HSTAT);
  float* ystat=(float*)(ws+WSO_YSTAT);
  float* xstat=(float*)(ws+WSO_XSTAT);
  unsigned short* H16=(unsigned short*)(ws+WSO_H16);
  float* NSf=(float*)(smem+LDS_NS);
  float* BIAS=(float*)(smem+LDS_BIAS);
  float* SGSB=(float*)(smem+LDS_SGSB);

  // one-time init: weights -> LDS
  {
    int lc=tid>>3;
    int cgl=(lc>>4)*1024 + wr*16 + (lc&15);
    const unsigned short* src=WT + ((size_t)li*2048+cgl)*2048;
    char* dcol = smem + LDS_W + lc*4096;
    int sw2=(lc&7)<<4;
    #pragma unroll
    for (int n=0;n<32;++n){
      int q=sseg+n*8;
      uint4 d=*(const uint4*)(src+q*8);
      *(uint4*)(dcol + ((q*16)^sw2)) = d;
    }
  }
  if (li==0){
    float* g32=(float*)(smem+LDS_GB);
    for (int k=tid;k<1024;k+=TPB){ g32[k]=pg[k]; g32[1024+k]=pb[k]; }
  } else {
    unsigned* g16=(unsigned*)(smem+LDS_GB);
    for (int k=tid;k<512;k+=TPB){
      g16[k]    =pk2h(pg[li*1024+2*k], pg[li*1024+2*k+1]);
      g16[512+k]=pk2h(pb[li*1024+2*k], pb[li*1024+2*k+1]);
    }
  }
  if (tid<16) BIAS[tid]=bfv[li*1024+wr*16+tid];
  else if (tid<32) BIAS[tid]=bcv[li*1024+wr*16+(tid-16)];
  if (li==3){
    if (tid<16) SGSB[tid]=sg[wr*16+tid];
    else if (tid<32) SGSB[tid]=sbv[wr*16+(tid-16)];
  }
  f32x2 sreg, pns={0.f,0.f};
  sreg.x = st0[(size_t)li*BD_ + (size_t)r0*D_ + wr*16+col];
  sreg.y = st0[(size_t)li*BD_ + (size_t)r1*D_ + wr*16+col];
  __syncthreads();

  const char* WF = smem + LDS_W + l15*4096;
  const char* WC = smem + LDS_W + (16+l15)*4096;
  const int swl = (l15&7)<<4;
  const unsigned* GBg16 = (const unsigned*)(smem+LDS_GB);
  const float* GBg32 = (const float*)(smem+LDS_GB);
  const int voA = l15*2048 + kq*2, voB = voA + 32768;
  const int vxA = l15*4096 + kq*4, vxB = vxA + 65536;
  const int vsA = l15*8, vsB = 128 + l15*8;

  for (int t=0; t<T_; ++t){
    // ---- poll 1: own-layer state(t) complete
    if (tid==0){
      const unsigned ow=64u*(unsigned)t;
      while (cldu(prog+li*64) < ow) __builtin_amdgcn_s_sleep(1);
    }
    __syncthreads();

    // ---- front-matter (li3 only: y[t-1])
    if (li==3){
      if (t>=1){
        const float* stY=ystat+(size_t)(t-1)*64;
        float gv=SGSB[col], bv=SGSB[16+col];
        float s1=cload1(stY+r0*2), s2=cload1(stY+r0*2+1);
        float m0=s1*(1.f/1024.f);
        float rs0=rsqrtf(s2*(1.f/1024.f)-m0*m0+EPSF);
        y[(size_t)(t-1)*BD_+(size_t)r0*D_+wr*16+col]=(pns.x-m0)*rs0*gv+bv;
        float s3=cload1(stY+r1*2), s4=cload1(stY+r1*2+1);
        float m1=s3*(1.f/1024.f);
        float rs1=rsqrtf(s4*(1.f/1024.f)-m1*m1+EPSF);
        y[(size_t)(t-1)*BD_+(size_t)r1*D_+wr*16+col]=(pns.y-m1)*rs1*gv+bv;
      }
      asm volatile("s_waitcnt vmcnt(0)" ::: "memory");
    }

    u64 sbS = (u64)(uintptr_t)(H16 + ((size_t)li*513 + (size_t)t)*32768);
    f32x4 accF0={0,0,0,0}, accF1={0,0,0,0}, accC0={0,0,0,0}, accC1={0,0,0,0};

    if (li==0){
      u64 sbH = (u64)(uintptr_t)(x + (size_t)t*BD_);
      u64 sbT = (u64)(uintptr_t)(xstat + (size_t)t*64);
      u32x4 pS[16]; u32x4 pX[32]; u32x2 tS0, tS1;
      // issue: S(16) -> T(2) -> X(32); total 50
      GLDX(pS[0],  voA+0*256, sbS); GLDX(pS[1],  voB+0*256, sbS);
      GLDX(pS[2],  voA+1*256, sbS); GLDX(pS[3],  voB+1*256, sbS);
      GLDX(pS[4],  voA+2*256, sbS); GLDX(pS[5],  voB+2*256, sbS);
      GLDX(pS[6],  voA+3*256, sbS); GLDX(pS[7],  voB+3*256, sbS);
      GLDX(pS[8],  voA+4*256, sbS); GLDX(pS[9],  voB+4*256, sbS);
      GLDX(pS[10], voA+5*256, sbS); GLDX(pS[11], voB+5*256, sbS);
      GLDX(pS[12], voA+6*256, sbS); GLDX(pS[13], voB+6*256, sbS);
      GLDX(pS[14], voA+7*256, sbS); GLDX(pS[15], voB+7*256, sbS);
      GLDX2(tS0, vsA, sbT); GLDX2(tS1, vsB, sbT);
      GLDX(pX[0],  vxA+0*512, sbH); GLDX(pX[1],  vxA+0*512+16, sbH); GLDX(pX[2],  vxB+0*512, sbH); GLDX(pX[3],  vxB+0*512+16, sbH);
      GLDX(pX[4],  vxA+1*512, sbH); GLDX(pX[5],  vxA+1*512+16, sbH); GLDX(pX[6],  vxB+1*512, sbH); GLDX(pX[7],  vxB+1*512+16, sbH);
      GLDX(pX[8],  vxA+2*512, sbH); GLDX(pX[9],  vxA+2*512+16, sbH); GLDX(pX[10], vxB+2*512, sbH); GLDX(pX[11], vxB+2*512+16, sbH);
      GLDX(pX[12], vxA+3*512, sbH); GLDX(pX[13], vxA+3*512+16, sbH); GLDX(pX[14], vxB+3*512, sbH); GLDX(pX[15], vxB+3*512+16, sbH);
      GLDX(pX[16], vxA+4*512, sbH); GLDX(pX[17], vxA+4*512+16, sbH); GLDX(pX[18], vxB+4*512, sbH); GLDX(pX[19], vxB+4*512+16, sbH);
      GLDX(pX[20], vxA+5*512, sbH); GLDX(pX[21], vxA+5*512+16, sbH); GLDX(pX[22], vxB+5*512, sbH); GLDX(pX[23], vxB+5*512+16, sbH);
      GLDX(pX[24], vxA+6*512, sbH); GLDX(pX[25], vxA+6*512+16, sbH); GLDX(pX[26], vxB+6*512, sbH); GLDX(pX[27], vxB+6*512+16, sbH);
      GLDX(pX[28], vxA+7*512, sbH); GLDX(pX[29], vxA+7*512+16, sbH); GLDX(pX[30], vxB+7*512, sbH); GLDX(pX[31], vxB+7*512+16, sbH);
      // compute state chunks as S lands
      PSI(0,48); PSI(1,46); PSI(2,44); PSI(3,42); PSI(4,40); PSI(5,38); PSI(6,36); PSI(7,34);
      // stats
      WAITV(32);
      f32x2 s01=__builtin_bit_cast(f32x2,tS0), s23=__builtin_bit_cast(f32x2,tS1);
      float mA=s01.x*(1.f/1024.f);
      float rsA=rsqrtf(s01.y*(1.f/1024.f)-mA*mA+EPSF), nmA=-mA*rsA;
      float mB=s23.x*(1.f/1024.f);
      float rsB=rsqrtf(s23.y*(1.f/1024.f)-mB*mB+EPSF), nmB=-mB*rsB;
      // x chunks
      PHX(0,28); PHX(1,24); PHX(2,20); PHX(3,16); PHX(4,12); PHX(5,8); PHX(6,4); PHX(7,0);
    } else {
      u64 sbH = (u64)(uintptr_t)(H16 + ((size_t)(li-1)*513 + (size_t)(t+1))*32768);
      u64 sbT = (u64)(uintptr_t)(hstat + ((size_t)(li-1)*512 + (size_t)t)*64);
      u32x4 pS[16]; u32x4 pH[16]; u32x2 tS0, tS1;
      // issue state loads (guarded by poll 1)
      GLDX(pS[0],  voA+0*256, sbS); GLDX(pS[1],  voB+0*256, sbS);
      GLDX(pS[2],  voA+1*256, sbS); GLDX(pS[3],  voB+1*256, sbS);
      GLDX(pS[4],  voA+2*256, sbS); GLDX(pS[5],  voB+2*256, sbS);
      GLDX(pS[6],  voA+3*256, sbS); GLDX(pS[7],  voB+3*256, sbS);
      GLDX(pS[8],  voA+4*256, sbS); GLDX(pS[9],  voB+4*256, sbS);
      GLDX(pS[10], voA+5*256, sbS); GLDX(pS[11], voB+5*256, sbS);
      GLDX(pS[12], voA+6*256, sbS); GLDX(pS[13], voB+6*256, sbS);
      GLDX(pS[14], voA+7*256, sbS); GLDX(pS[15], voB+7*256, sbS);
      // poll 2: upstream h(t) complete — overlapped with state loads in flight
      if (tid==0){
        const unsigned uw=64u*(unsigned)(t+1);
        while (cldu(prog+(li-1)*64) < uw) __builtin_amdgcn_s_sleep(1);
      }
      BARS;   // raw barrier (lgkm only) — does NOT drain vmcnt
      // issue stats + h loads
      GLDX2(tS0, vsA, sbT); GLDX2(tS1, vsB, sbT);
      GLDX(pH[0],  voA+0*256, sbH); GLDX(pH[1],  voB+0*256, sbH);
      GLDX(pH[2],  voA+1*256, sbH); GLDX(pH[3],  voB+1*256, sbH);
      GLDX(pH[4],  voA+2*256, sbH); GLDX(pH[5],  voB+2*256, sbH);
      GLDX(pH[6],  voA+3*256, sbH); GLDX(pH[7],  voB+3*256, sbH);
      GLDX(pH[8],  voA+4*256, sbH); GLDX(pH[9],  voB+4*256, sbH);
      GLDX(pH[10], voA+5*256, sbH); GLDX(pH[11], voB+5*256, sbH);
      GLDX(pH[12], voA+6*256, sbH); GLDX(pH[13], voB+6*256, sbH);
      GLDX(pH[14], voA+7*256, sbH); GLDX(pH[15], voB+7*256, sbH);
      // compute state chunks as S lands
      PSI(0,32); PSI(1,30); PSI(2,28); PSI(3,26); PSI(4,24); PSI(5,22); PSI(6,20); PSI(7,18);
      // stats
      WAITV(16);
      f32x2 s01=__builtin_bit_cast(f32x2,tS0), s23=__builtin_bit_cast(f32x2,tS1);
      float mA=s01.x*(1.f/1024.f);
      float rsAf=rsqrtf(s01.y*(1.f/1024.f)-mA*mA+EPSF), nmAf=-mA*rsAf;
      float mB=s23.x*(1.f/1024.f);
      float rsBf=rsqrtf(s23.y*(1.f/1024.f)-mB*mB+EPSF), nmBf=-mB*rsBf;
      const _Float16 hrA=(_Float16)rsAf, hmA=(_Float16)nmAf, hrB=(_Float16)rsBf, hmB=(_Float16)nmBf;
      const f16x8 rsA8={hrA,hrA,hrA,hrA,hrA,hrA,hrA,hrA};
      const f16x8 nmA8={hmA,hmA,hmA,hmA,hmA,hmA,hmA,hmA};
      const f16x8 rsB8={hrB,hrB,hrB,hrB,hrB,hrB,hrB,hrB};
      const f16x8 nmB8={hmB,hmB,hmB,hmB,hmB,hmB,hmB,hmB};
      // h chunks
      PHN(0,14); PHN(1,12); PHN(2,10); PHN(3,8); PHN(4,6); PHN(5,4); PHN(6,2); PHN(7,0);
    }

    *(f32x4*)(smem+LDS_DUMP + (((v*4+0)*64+lane)<<4)) = accF0;
    *(f32x4*)(smem+LDS_DUMP + (((v*4+1)*64+lane)<<4)) = accF1;
    *(f32x4*)(smem+LDS_DUMP + (((v*4+2)*64+lane)<<4)) = accC0;
    *(f32x4*)(smem+LDS_DUMP + (((v*4+3)*64+lane)<<4)) = accC1;
    BARS;

    {
      const int rtl = v>>1;
      const int lg20 = (v&1)*2, lg21 = (v&1)*2+1;
      float fF0=0.f,fF1=0.f,fC0=0.f,fC1=0.f;
      #pragma unroll
      for (int v2=0;v2<4;++v2){
        const char* db = smem+LDS_DUMP + v2*4096;
        fF0 += *(const float*)(db + (((0+rtl)*64 + lg20*16+col)<<4) + rp*4);
        fF1 += *(const float*)(db + (((0+rtl)*64 + lg21*16+col)<<4) + rp*4);
        fC0 += *(const float*)(db + (((2+rtl)*64 + lg20*16+col)<<4) + rp*4);
        fC1 += *(const float*)(db + (((2+rtl)*64 + lg21*16+col)<<4) + rp*4);
      }
      float bfc=BIAS[col], bcc=BIAS[16+col];
      float preF0=fminf(fmaxf(fF0+bfc,-30.f),30.f);
      float preC0=fminf(fmaxf(fC0+bcc,-30.f),30.f);
      float preF1=fminf(fmaxf(fF1+bfc,-30.f),30.f);
      float preC1=fminf(fmaxf(fC1+bcc,-30.f),30.f);
      float fg0=1.f/(1.f+__expf(-preF0)), e0=__expf(-2.f*preC0);
      float cd0=(1.f-e0)/(1.f+e0);
      float fg1=1.f/(1.f+__expf(-preF1)), e1=__expf(-2.f*preC1);
      float cd1=(1.f-e1)/(1.f+e1);
      float ns0=fg0*sreg.x+(1.f-fg0)*cd0;
      float ns1=fg1*sreg.y+(1.f-fg1)*cd1;
      sreg.x=ns0; sreg.y=ns1;
      if (li==3){ pns.x=ns0; pns.y=ns1; }
      float a1=ns0, a2=ns0*ns0, a3=ns1, a4=ns1*ns1;
      #pragma unroll
      for (int m=1;m<16;m<<=1){
        a1+=__shfl_xor(a1,m); a2+=__shfl_xor(a2,m);
        a3+=__shfl_xor(a3,m); a4+=__shfl_xor(a4,m);
      }
      float* stadd=(li<3)? (hstat+((size_t)li*512+t)*64) : (ystat+(size_t)t*64);
      if (col==0){
        atomicAdd(stadd+r0*2,   a1); atomicAdd(stadd+r0*2+1, a2);
        atomicAdd(stadd+r1*2,   a3); atomicAdd(stadd+r1*2+1, a4);
      }
      NSf[r0*NSTR+col]=ns0;
      NSf[r1*NSTR+col]=ns1;
    }
    BARS;

    if (lane<16){
      int row = v*8 + (lane>>1), hf = lane&1;
      const float* nr = NSf + row*NSTR + hf*8;
      f32x4 q0 = *(const f32x4*)nr, q1 = *(const f32x4*)(nr+4);
      unsigned w0=pk2h(q0[0],q0[1]), w1=pk2h(q0[2],q0[3]);
      unsigned w2=pk2h(q1[0],q1[1]), w3=pk2h(q1[2],q1[3]);
      unsigned short* sd = H16 + ((size_t)li*513 + (size_t)(t+1))*32768 + row*1024 + wr*16 + hf*8;
      cstore16(sd, w0, w1, w2, w3);
      if (t==T_-1){
        float* op = ostate + (size_t)li*BD_ + (size_t)row*D_ + wr*16 + hf*8;
        *(f32x4*)op = q0; *(f32x4*)(op+4) = q1;
      }
    }

    // ---- arrive
    asm volatile("s_waitcnt vmcnt(0)" ::: "memory");
    __syncthreads();
    if (tid==0)
      __hip_atomic_fetch_add(prog+li*64, 1u, __ATOMIC_RELAXED, __HIP_MEMORY_SCOPE_AGENT);
  }

  // ---- tail: y[511]
  if (li==3){
    if (tid==0){
      while (cldu(prog+3*64) < 64u*(unsigned)T_) __builtin_amdgcn_s_sleep(1);
    }
    __syncthreads();
    const float* stY=ystat+(size_t)(T_-1)*64;
    float gv=SGSB[col], bv=SGSB[16+col];
    float s1=cload1(stY+r0*2), s2=cload1(stY+r0*2+1);
    float m0=s1*(1.f/1024.f);
    float rs0=rsqrtf(s2*(1.f/1024.f)-m0*m0+EPSF);
    y[(size_t)(T_-1)*BD_+(size_t)r0*D_+wr*16+col]=(pns.x-m0)*rs0*gv+bv;
    float s3=cload1(stY+r1*2), s4=cload1(stY+r1*2+1);
    float m1=s3*(1.f/1024.f);
    float rs1=rsqrtf(s4*(1.f/1024.f)-m1*m1+EPSF);
    y[(size_t)(T_-1)*BD_+(size_t)r1*D_+wr*16+col]=(pns.y-m1)*rs1*gv+bv;
  }
}

extern "C" void kernel_launch(void* const* d_in, const int* in_sizes, int n_in,
                              void* d_out, int out_size, void* d_ws, size_t ws_size,
                              hipStream_t stream){
  (void)in_sizes; (void)n_in; (void)out_size; (void)ws_size;
  const float* x   = (const float*)d_in[0];
  const float* st0 = (const float*)d_in[1];
  const float* Wf  = (const float*)d_in[2];
  const float* Uf  = (const float*)d_in[3];
  const float* bfv = (const float*)d_in[4];
  const float* Wc  = (const float*)d_in[5];
  const float* Uc  = (const float*)d_in[6];
  const float* bcv = (const float*)d_in[7];
  const float* pg  = (const float*)d_in[8];
  const float* pb  = (const float*)d_in[9];
  const float* sg  = (const float*)d_in[10];
  const float* sbv = (const float*)d_in[11];

  float* y      = (float*)d_out;
  float* ostate = y + (size_t)T_*BD_;
  char* ws = (char*)d_ws;

  (void)hipMemsetAsync(ws, 0, WSO_ZEND, stream);
  hipLaunchKernelGGL(crs_prepass, dim3(8192), dim3(256), 0, stream,
                     Wf, Uf, Wc, Uc, (unsigned short*)(ws+WSO_WT));
  hipLaunchKernelGGL(crs_prep2, dim3(T_+L_), dim3(256), 0, stream,
                     x, st0, (float*)(ws+WSO_XSTAT), (unsigned short*)(ws+WSO_H16));
  (void)hipFuncSetAttribute((const void*)crs_main, hipFuncAttributeMaxDynamicSharedMemorySize, LDS_TOTAL);
  hipLaunchKernelGGL(crs_main, dim3(NWG), dim3(TPB), LDS_TOTAL, stream,
                     x, st0, bfv, bcv, pg, pb, sg, sbv, y, ostate,
                     (const unsigned short*)(ws+WSO_WT), ws);
}

// Round 14
// 5760.771 us; speedup vs baseline: 1.4403x; 1.4403x over previous
//
#include <hip/hip_runtime.h>
#include <cstdint>
#include <cstddef>

#define T_ 512
#define B_ 32
#define D_ 1024
#define L_ 4
#define BD_ (B_*D_)
#define TPB 256
#define NWG 256
#define EPSF 1e-5f

typedef _Float16 f16x8 __attribute__((ext_vector_type(8)));
typedef float f32x4 __attribute__((ext_vector_type(4)));
typedef float f32x2 __attribute__((ext_vector_type(2)));
typedef unsigned int u32x4 __attribute__((ext_vector_type(4)));
typedef unsigned long long u64;

// workspace layout (bytes)
#define WSO_PROG   0          // 4 layer progress counters, 256B apart (memset 4096)
#define WSO_WT     1048576    // fp16 weights, 32MB
#define WSO_H16    34603008   // [4][513][32][1024] fp16 state/h streams

// LDS layout (bytes)
#define LDS_W     0
#define LDS_DUMP  131072
#define LDS_GB    147456
#define LDS_NS    155904
#define LDS_BIAS  158464
#define LDS_SGSB  158592
#define LDS_RED   158720      // h-stat partials [4][16] f32x4 (1KB) + state-stat partials (1KB)
#define LDS_TOTAL 160768
#define NSTR 20

__device__ __forceinline__ unsigned pk2h(float a, float b){
  _Float16 ha=(_Float16)a, hb=(_Float16)b;
  return (unsigned)__builtin_bit_cast(unsigned short,ha) |
         ((unsigned)__builtin_bit_cast(unsigned short,hb)<<16);
}
__device__ __forceinline__ unsigned cldu(const unsigned* p){
  return __hip_atomic_load(p,__ATOMIC_RELAXED,__HIP_MEMORY_SCOPE_AGENT);
}
__device__ __forceinline__ void cstore16(unsigned short* p, unsigned w0, unsigned w1, unsigned w2, unsigned w3){
  u64 lo=((u64)w1<<32)|w0, hi=((u64)w3<<32)|w2;
  __hip_atomic_store((u64*)(void*)p,     lo, __ATOMIC_RELAXED, __HIP_MEMORY_SCOPE_AGENT);
  __hip_atomic_store((u64*)(void*)(p+4), hi, __ATOMIC_RELAXED, __HIP_MEMORY_SCOPE_AGENT);
}

#define GLDX(d,vo,sb)  asm volatile("global_load_dwordx4 %0, %1, %2" : "=v"(d) : "v"(vo), "s"(sb) : "memory")
#define WAITV(N) do{ asm volatile("s_waitcnt vmcnt(" #N ")" ::: "memory"); __builtin_amdgcn_sched_barrier(0); }while(0)
#define BARS do{ asm volatile("s_waitcnt lgkmcnt(0)" ::: "memory"); __builtin_amdgcn_s_barrier(); }while(0)

#define MM(cc) do{ \
    const int kb_=(((cc)*128+kq))*2; \
    f16x8 bF=*(const f16x8*)(WF + (kb_^swl)); \
    f16x8 bC=*(const f16x8*)(WC + (kb_^swl)); \
    accF0=__builtin_amdgcn_mfma_f32_16x16x32_f16(a0,bF,accF0,0,0,0); \
    accF1=__builtin_amdgcn_mfma_f32_16x16x32_f16(a1,bF,accF1,0,0,0); \
    accC0=__builtin_amdgcn_mfma_f32_16x16x32_f16(a0,bC,accC0,0,0,0); \
    accC1=__builtin_amdgcn_mfma_f32_16x16x32_f16(a1,bC,accC1,0,0,0); \
  }while(0)

// state chunk i (fused-k chunk 8+i): raw fp16, consumed as loads land
#define PSI(i,NW) do{ WAITV(NW); \
    f16x8 a0=__builtin_bit_cast(f16x8,pS[2*(i)]); \
    f16x8 a1=__builtin_bit_cast(f16x8,pS[2*(i)+1]); \
    MM(8+(i)); }while(0)

// h chunk c (li>0): fp16 + packed-fp16 LN; no vm wait (all landed)
#define PHN(c) do{ \
    f16x8 a0=__builtin_bit_cast(f16x8,pH[2*(c)]); \
    f16x8 a1=__builtin_bit_cast(f16x8,pH[2*(c)+1]); \
    const int kf_=(c)*128+kq; \
    f16x8 g8=*(const f16x8*)(GBg16+(kf_>>1)); \
    f16x8 b8=*(const f16x8*)(GBg16+512+(kf_>>1)); \
    a0=a0*rsA8+nmA8; a0=a0*g8+b8; \
    a1=a1*rsB8+nmB8; a1=a1*g8+b8; \
    MM(c); }while(0)

// x chunk c (li==0): fp32 + f32 LN; no vm wait
#define PHX(c) do{ \
    f32x4 xa0=__builtin_bit_cast(f32x4,pX[4*(c)]),   xa1=__builtin_bit_cast(f32x4,pX[4*(c)+1]); \
    f32x4 xb0=__builtin_bit_cast(f32x4,pX[4*(c)+2]), xb1=__builtin_bit_cast(f32x4,pX[4*(c)+3]); \
    const int kf_=(c)*128+kq; \
    f32x4 g0=*(const f32x4*)(GBg32+kf_), g1=*(const f32x4*)(GBg32+kf_+4); \
    f32x4 q0=*(const f32x4*)(GBg32+1024+kf_), q1=*(const f32x4*)(GBg32+1024+kf_+4); \
    f16x8 a0,a1; \
    a0[0]=(_Float16)((xa0[0]*rsA+nmA)*g0[0]+q0[0]); a0[1]=(_Float16)((xa0[1]*rsA+nmA)*g0[1]+q0[1]); \
    a0[2]=(_Float16)((xa0[2]*rsA+nmA)*g0[2]+q0[2]); a0[3]=(_Float16)((xa0[3]*rsA+nmA)*g0[3]+q0[3]); \
    a0[4]=(_Float16)((xa1[0]*rsA+nmA)*g1[0]+q1[0]); a0[5]=(_Float16)((xa1[1]*rsA+nmA)*g1[1]+q1[1]); \
    a0[6]=(_Float16)((xa1[2]*rsA+nmA)*g1[2]+q1[2]); a0[7]=(_Float16)((xa1[3]*rsA+nmA)*g1[3]+q1[3]); \
    a1[0]=(_Float16)((xb0[0]*rsB+nmB)*g0[0]+q0[0]); a1[1]=(_Float16)((xb0[1]*rsB+nmB)*g0[1]+q0[1]); \
    a1[2]=(_Float16)((xb0[2]*rsB+nmB)*g0[2]+q0[2]); a1[3]=(_Float16)((xb0[3]*rsB+nmB)*g0[3]+q0[3]); \
    a1[4]=(_Float16)((xb1[0]*rsB+nmB)*g1[0]+q1[0]); a1[5]=(_Float16)((xb1[1]*rsB+nmB)*g1[1]+q1[1]); \
    a1[6]=(_Float16)((xb1[2]*rsB+nmB)*g1[2]+q1[2]); a1[7]=(_Float16)((xb1[3]*rsB+nmB)*g1[3]+q1[3]); \
    MM(c); }while(0)

// ---------------- pre-pass 1: weights -> fp16 transposed fused layout ----------------
extern "C" __global__ void __launch_bounds__(256,1) crs_prepass(
    const float* __restrict__ Wf, const float* __restrict__ Uf,
    const float* __restrict__ Wc, const float* __restrict__ Uc,
    unsigned short* __restrict__ WT)
{
  int bid = blockIdx.x;
  int kt  = bid & 15;
  int ct  = (bid>>4) & 31;
  int sel = (bid>>9) & 3;
  int i   = bid >> 11;
  int tid = threadIdx.x;
  int kq  = tid >> 5;
  int cc  = tid & 31;
  const float* sp;
  if      (sel==0) sp = Wf;
  else if (sel==1) sp = Uf;
  else if (sel==2) sp = Wc;
  else             sp = Uc;
  sp += (size_t)i * 1048576;
  int cl = ct*32 + cc;
  int k0 = kt*64 + kq*8;
  float f[8];
  #pragma unroll
  for (int e=0;e<8;++e){ f[e] = sp[(size_t)(k0+e)*1024 + cl]; }
  int cg = ((sel>>1) ? 1024 : 0) + cl;
  int ks = sel & 1;
  size_t idx = ((size_t)(i*2048 + cg)*2 + ks)*1024 + k0;
  uint4 pk;
  pk.x = pk2h(f[0], f[1]);
  pk.y = pk2h(f[2], f[3]);
  pk.z = pk2h(f[4], f[5]);
  pk.w = pk2h(f[6], f[7]);
  *(uint4*)(WT + idx) = pk;
}

// ---------------- pre-pass 2: initial state -> H16 slot 0 (4 blocks) ----------------
extern "C" __global__ void __launch_bounds__(256,1) crs_prep2(
    const float* __restrict__ st0, unsigned short* __restrict__ H16)
{
  int i2=blockIdx.x, tid=threadIdx.x;
  int rr=tid>>3, ss=tid&7;
  const float4* p4=(const float4*)(st0+(size_t)i2*BD_+rr*1024+ss*128);
  uint4* dst=(uint4*)(H16+(size_t)i2*513*32768+rr*1024+ss*128);
  #pragma unroll
  for (int q=0;q<16;++q){
    float4 a=p4[2*q], b=p4[2*q+1];
    uint4 pk; pk.x=pk2h(a.x,a.y); pk.y=pk2h(a.z,a.w); pk.z=pk2h(b.x,b.y); pk.w=pk2h(b.z,b.w);
    dst[q]=pk;
  }
}

// ---------------- main persistent kernel: dataflow + consumer-side LN stats ----------------
extern "C" __global__ void __launch_bounds__(TPB,1) crs_main(
    const float* __restrict__ x, const float* __restrict__ st0,
    const float* __restrict__ bfv, const float* __restrict__ bcv,
    const float* __restrict__ pg, const float* __restrict__ pb,
    const float* __restrict__ sg, const float* __restrict__ sbv,
    float* __restrict__ y, float* __restrict__ ostate,
    const unsigned short* __restrict__ WT, char* __restrict__ ws)
{
  extern __shared__ char smem[];
  const int tid=threadIdx.x, w=blockIdx.x;
  const int li=w>>6, wr=w&63;
  const int lane=tid&63, v=tid>>6;
  const int l15=lane&15, lg=(lane>>4)&3;
  const int kq = v*32 + lg*8;
  const int col=lane&15, rp=lane>>4;
  const int r0=v*8+rp, r1=v*8+4+rp;
  const int sseg=tid&7;

  unsigned* prog=(unsigned*)(ws+WSO_PROG);
  unsigned short* H16=(unsigned short*)(ws+WSO_H16);
  float* NSf=(float*)(smem+LDS_NS);
  float* BIAS=(float*)(smem+LDS_BIAS);
  float* SGSB=(float*)(smem+LDS_SGSB);
  char* RED0=smem+LDS_RED;           // h-stat partials [v][l15] f32x4
  char* RED1=smem+LDS_RED+1024;      // state-stat partials (li3)

  // one-time init: weights -> LDS
  {
    int lc=tid>>3;
    int cgl=(lc>>4)*1024 + wr*16 + (lc&15);
    const unsigned short* src=WT + ((size_t)li*2048+cgl)*2048;
    char* dcol = smem + LDS_W + lc*4096;
    int sw2=(lc&7)<<4;
    #pragma unroll
    for (int n=0;n<32;++n){
      int q=sseg+n*8;
      uint4 d=*(const uint4*)(src+q*8);
      *(uint4*)(dcol + ((q*16)^sw2)) = d;
    }
  }
  if (li==0){
    float* g32=(float*)(smem+LDS_GB);
    for (int k=tid;k<1024;k+=TPB){ g32[k]=pg[k]; g32[1024+k]=pb[k]; }
  } else {
    unsigned* g16=(unsigned*)(smem+LDS_GB);
    for (int k=tid;k<512;k+=TPB){
      g16[k]    =pk2h(pg[li*1024+2*k], pg[li*1024+2*k+1]);
      g16[512+k]=pk2h(pb[li*1024+2*k], pb[li*1024+2*k+1]);
    }
  }
  if (tid<16) BIAS[tid]=bfv[li*1024+wr*16+tid];
  else if (tid<32) BIAS[tid]=bcv[li*1024+wr*16+(tid-16)];
  if (li==3){
    if (tid<16) SGSB[tid]=sg[wr*16+tid];
    else if (tid<32) SGSB[tid]=sbv[wr*16+(tid-16)];
  }
  f32x2 sreg, pns={0.f,0.f};
  sreg.x = st0[(size_t)li*BD_ + (size_t)r0*D_ + wr*16+col];
  sreg.y = st0[(size_t)li*BD_ + (size_t)r1*D_ + wr*16+col];
  __syncthreads();

  const char* WF = smem + LDS_W + l15*4096;
  const char* WC = smem + LDS_W + (16+l15)*4096;
  const int swl = (l15&7)<<4;
  const unsigned* GBg16 = (const unsigned*)(smem+LDS_GB);
  const float* GBg32 = (const float*)(smem+LDS_GB);
  const int voA = l15*2048 + kq*2, voB = voA + 32768;
  const int vxA = l15*4096 + kq*4, vxB = vxA + 65536;

  for (int t=0; t<T_; ++t){
    // ---- poll 1: own-layer state(t) ready
    if (tid==0){
      const unsigned ow=64u*(unsigned)t;
      while (cldu(prog+li*64) < ow) __builtin_amdgcn_s_sleep(1);
    }
    __syncthreads();

    u64 sbS = (u64)(uintptr_t)(H16 + ((size_t)li*513 + (size_t)t)*32768);
    f32x4 accF0={0,0,0,0}, accF1={0,0,0,0}, accC0={0,0,0,0}, accC1={0,0,0,0};

    if (li==0){
      u64 sbH = (u64)(uintptr_t)(x + (size_t)t*BD_);
      u32x4 pS[16]; u32x4 pX[32];
      GLDX(pS[0],  voA+0*256, sbS); GLDX(pS[1],  voB+0*256, sbS);
      GLDX(pS[2],  voA+1*256, sbS); GLDX(pS[3],  voB+1*256, sbS);
      GLDX(pS[4],  voA+2*256, sbS); GLDX(pS[5],  voB+2*256, sbS);
      GLDX(pS[6],  voA+3*256, sbS); GLDX(pS[7],  voB+3*256, sbS);
      GLDX(pS[8],  voA+4*256, sbS); GLDX(pS[9],  voB+4*256, sbS);
      GLDX(pS[10], voA+5*256, sbS); GLDX(pS[11], voB+5*256, sbS);
      GLDX(pS[12], voA+6*256, sbS); GLDX(pS[13], voB+6*256, sbS);
      GLDX(pS[14], voA+7*256, sbS); GLDX(pS[15], voB+7*256, sbS);
      GLDX(pX[0],  vxA+0*512, sbH); GLDX(pX[1],  vxA+0*512+16, sbH); GLDX(pX[2],  vxB+0*512, sbH); GLDX(pX[3],  vxB+0*512+16, sbH);
      GLDX(pX[4],  vxA+1*512, sbH); GLDX(pX[5],  vxA+1*512+16, sbH); GLDX(pX[6],  vxB+1*512, sbH); GLDX(pX[7],  vxB+1*512+16, sbH);
      GLDX(pX[8],  vxA+2*512, sbH); GLDX(pX[9],  vxA+2*512+16, sbH); GLDX(pX[10], vxB+2*512, sbH); GLDX(pX[11], vxB+2*512+16, sbH);
      GLDX(pX[12], vxA+3*512, sbH); GLDX(pX[13], vxA+3*512+16, sbH); GLDX(pX[14], vxB+3*512, sbH); GLDX(pX[15], vxB+3*512+16, sbH);
      GLDX(pX[16], vxA+4*512, sbH); GLDX(pX[17], vxA+4*512+16, sbH); GLDX(pX[18], vxB+4*512, sbH); GLDX(pX[19], vxB+4*512+16, sbH);
      GLDX(pX[20], vxA+5*512, sbH); GLDX(pX[21], vxA+5*512+16, sbH); GLDX(pX[22], vxB+5*512, sbH); GLDX(pX[23], vxB+5*512+16, sbH);
      GLDX(pX[24], vxA+6*512, sbH); GLDX(pX[25], vxA+6*512+16, sbH); GLDX(pX[26], vxB+6*512, sbH); GLDX(pX[27], vxB+6*512+16, sbH);
      GLDX(pX[28], vxA+7*512, sbH); GLDX(pX[29], vxA+7*512+16, sbH); GLDX(pX[30], vxB+7*512, sbH); GLDX(pX[31], vxB+7*512+16, sbH);
      PSI(0,46); PSI(1,44); PSI(2,42); PSI(3,40); PSI(4,38); PSI(5,36); PSI(6,34); PSI(7,32);
      WAITV(0);
      // per-lane x sums
      float sA=0.f,qA=0.f,sB=0.f,qB=0.f;
      #pragma unroll
      for (int c2=0;c2<8;++c2){
        f32x4 u0=__builtin_bit_cast(f32x4,pX[4*c2]),   u1=__builtin_bit_cast(f32x4,pX[4*c2+1]);
        f32x4 w0=__builtin_bit_cast(f32x4,pX[4*c2+2]), w1=__builtin_bit_cast(f32x4,pX[4*c2+3]);
        #pragma unroll
        for (int j=0;j<4;++j){
          sA+=u0[j]; qA+=u0[j]*u0[j]; sA+=u1[j]; qA+=u1[j]*u1[j];
          sB+=w0[j]; qB+=w0[j]*w0[j]; sB+=w1[j]; qB+=w1[j]*w1[j];
        }
      }
      sA+=__shfl_xor(sA,16); qA+=__shfl_xor(qA,16); sB+=__shfl_xor(sB,16); qB+=__shfl_xor(qB,16);
      sA+=__shfl_xor(sA,32); qA+=__shfl_xor(qA,32); sB+=__shfl_xor(sB,32); qB+=__shfl_xor(qB,32);
      if (lane<16){ f32x4 pk={sA,qA,sB,qB}; *(f32x4*)(RED0+((v*16+lane)<<4))=pk; }
      BARS;
      f32x4 hp={0.f,0.f,0.f,0.f};
      #pragma unroll
      for (int vv=0;vv<4;++vv) hp += *(const f32x4*)(RED0+((vv*16+l15)<<4));
      float mA=hp.x*(1.f/1024.f);
      float rsA=rsqrtf(hp.y*(1.f/1024.f)-mA*mA+EPSF), nmA=-mA*rsA;
      float mB=hp.z*(1.f/1024.f);
      float rsB=rsqrtf(hp.w*(1.f/1024.f)-mB*mB+EPSF), nmB=-mB*rsB;
      PHX(0); PHX(1); PHX(2); PHX(3); PHX(4); PHX(5); PHX(6); PHX(7);
    } else {
      u64 sbH = (u64)(uintptr_t)(H16 + ((size_t)(li-1)*513 + (size_t)(t+1))*32768);
      u32x4 pS[16]; u32x4 pH[16];
      GLDX(pS[0],  voA+0*256, sbS); GLDX(pS[1],  voB+0*256, sbS);
      GLDX(pS[2],  voA+1*256, sbS); GLDX(pS[3],  voB+1*256, sbS);
      GLDX(pS[4],  voA+2*256, sbS); GLDX(pS[5],  voB+2*256, sbS);
      GLDX(pS[6],  voA+3*256, sbS); GLDX(pS[7],  voB+3*256, sbS);
      GLDX(pS[8],  voA+4*256, sbS); GLDX(pS[9],  voB+4*256, sbS);
      GLDX(pS[10], voA+5*256, sbS); GLDX(pS[11], voB+5*256, sbS);
      GLDX(pS[12], voA+6*256, sbS); GLDX(pS[13], voB+6*256, sbS);
      GLDX(pS[14], voA+7*256, sbS); GLDX(pS[15], voB+7*256, sbS);
      // poll 2: upstream h(t) ready — overlapped with state loads in flight
      if (tid==0){
        const unsigned uw=64u*(unsigned)(t+1);
        while (cldu(prog+(li-1)*64) < uw) __builtin_amdgcn_s_sleep(1);
      }
      BARS;   // raw barrier: does NOT drain vmcnt
      GLDX(pH[0],  voA+0*256, sbH); GLDX(pH[1],  voB+0*256, sbH);
      GLDX(pH[2],  voA+1*256, sbH); GLDX(pH[3],  voB+1*256, sbH);
      GLDX(pH[4],  voA+2*256, sbH); GLDX(pH[5],  voB+2*256, sbH);
      GLDX(pH[6],  voA+3*256, sbH); GLDX(pH[7],  voB+3*256, sbH);
      GLDX(pH[8],  voA+4*256, sbH); GLDX(pH[9],  voB+4*256, sbH);
      GLDX(pH[10], voA+5*256, sbH); GLDX(pH[11], voB+5*256, sbH);
      GLDX(pH[12], voA+6*256, sbH); GLDX(pH[13], voB+6*256, sbH);
      GLDX(pH[14], voA+7*256, sbH); GLDX(pH[15], voB+7*256, sbH);
      PSI(0,30); PSI(1,28); PSI(2,26); PSI(3,24); PSI(4,22); PSI(5,20); PSI(6,18); PSI(7,16);
      WAITV(0);
      // per-lane h sums (+ state sums for li3 y-stats)
      float sA=0.f,qA=0.f,sB=0.f,qB=0.f;
      #pragma unroll
      for (int c2=0;c2<8;++c2){
        f16x8 hA=__builtin_bit_cast(f16x8,pH[2*c2]);
        f16x8 hB=__builtin_bit_cast(f16x8,pH[2*c2+1]);
        #pragma unroll
        for (int j=0;j<8;++j){
          float fa=(float)hA[j], fb=(float)hB[j];
          sA+=fa; qA+=fa*fa; sB+=fb; qB+=fb*fb;
        }
      }
      sA+=__shfl_xor(sA,16); qA+=__shfl_xor(qA,16); sB+=__shfl_xor(sB,16); qB+=__shfl_xor(qB,16);
      sA+=__shfl_xor(sA,32); qA+=__shfl_xor(qA,32); sB+=__shfl_xor(sB,32); qB+=__shfl_xor(qB,32);
      if (lane<16){ f32x4 pk={sA,qA,sB,qB}; *(f32x4*)(RED0+((v*16+lane)<<4))=pk; }
      if (li==3){
        float sS=0.f,qS=0.f,sT=0.f,qT=0.f;
        #pragma unroll
        for (int c2=0;c2<8;++c2){
          f16x8 tA=__builtin_bit_cast(f16x8,pS[2*c2]);
          f16x8 tB=__builtin_bit_cast(f16x8,pS[2*c2+1]);
          #pragma unroll
          for (int j=0;j<8;++j){
            float fa=(float)tA[j], fb=(float)tB[j];
            sS+=fa; qS+=fa*fa; sT+=fb; qT+=fb*fb;
          }
        }
        sS+=__shfl_xor(sS,16); qS+=__shfl_xor(qS,16); sT+=__shfl_xor(sT,16); qT+=__shfl_xor(qT,16);
        sS+=__shfl_xor(sS,32); qS+=__shfl_xor(qS,32); sT+=__shfl_xor(sT,32); qT+=__shfl_xor(qT,32);
        if (lane<16){ f32x4 pk={sS,qS,sT,qT}; *(f32x4*)(RED1+((v*16+lane)<<4))=pk; }
      }
      BARS;
      f32x4 hp={0.f,0.f,0.f,0.f};
      #pragma unroll
      for (int vv=0;vv<4;++vv) hp += *(const f32x4*)(RED0+((vv*16+l15)<<4));
      float mAf=hp.x*(1.f/1024.f);
      float rsAf=rsqrtf(hp.y*(1.f/1024.f)-mAf*mAf+EPSF), nmAf=-mAf*rsAf;
      float mBf=hp.z*(1.f/1024.f);
      float rsBf=rsqrtf(hp.w*(1.f/1024.f)-mBf*mBf+EPSF), nmBf=-mBf*rsBf;
      const _Float16 hrA=(_Float16)rsAf, hmA=(_Float16)nmAf, hrB=(_Float16)rsBf, hmB=(_Float16)nmBf;
      const f16x8 rsA8={hrA,hrA,hrA,hrA,hrA,hrA,hrA,hrA};
      const f16x8 nmA8={hmA,hmA,hmA,hmA,hmA,hmA,hmA,hmA};
      const f16x8 rsB8={hrB,hrB,hrB,hrB,hrB,hrB,hrB,hrB};
      const f16x8 nmB8={hmB,hmB,hmB,hmB,hmB,hmB,hmB,hmB};
      // li3: write y[t-1] from pns + state-tile stats (state tile == ns(t-1))
      if (li==3 && t>=1){
        f32x4 sp0={0.f,0.f,0.f,0.f}, sp1={0.f,0.f,0.f,0.f};
        #pragma unroll
        for (int vv=0;vv<4;++vv){
          sp0 += *(const f32x4*)(RED1+((vv*16+(r0&15))<<4));
          sp1 += *(const f32x4*)(RED1+((vv*16+(r1&15))<<4));
        }
        float gv=SGSB[col], bv=SGSB[16+col];
        float s0=(r0<16)? sp0.x : sp0.z, q0=(r0<16)? sp0.y : sp0.w;
        float m0=s0*(1.f/1024.f);
        float rs0=rsqrtf(q0*(1.f/1024.f)-m0*m0+EPSF);
        y[(size_t)(t-1)*BD_+(size_t)r0*D_+wr*16+col]=(pns.x-m0)*rs0*gv+bv;
        float s1v=(r1<16)? sp1.x : sp1.z, q1v=(r1<16)? sp1.y : sp1.w;
        float m1=s1v*(1.f/1024.f);
        float rs1=rsqrtf(q1v*(1.f/1024.f)-m1*m1+EPSF);
        y[(size_t)(t-1)*BD_+(size_t)r1*D_+wr*16+col]=(pns.y-m1)*rs1*gv+bv;
      }
      PHN(0); PHN(1); PHN(2); PHN(3); PHN(4); PHN(5); PHN(6); PHN(7);
    }

    *(f32x4*)(smem+LDS_DUMP + (((v*4+0)*64+lane)<<4)) = accF0;
    *(f32x4*)(smem+LDS_DUMP + (((v*4+1)*64+lane)<<4)) = accF1;
    *(f32x4*)(smem+LDS_DUMP + (((v*4+2)*64+lane)<<4)) = accC0;
    *(f32x4*)(smem+LDS_DUMP + (((v*4+3)*64+lane)<<4)) = accC1;
    BARS;

    {
      const int rtl = v>>1;
      const int lg20 = (v&1)*2, lg21 = (v&1)*2+1;
      float fF0=0.f,fF1=0.f,fC0=0.f,fC1=0.f;
      #pragma unroll
      for (int v2=0;v2<4;++v2){
        const char* db = smem+LDS_DUMP + v2*4096;
        fF0 += *(const float*)(db + (((0+rtl)*64 + lg20*16+col)<<4) + rp*4);
        fF1 += *(const float*)(db + (((0+rtl)*64 + lg21*16+col)<<4) + rp*4);
        fC0 += *(const float*)(db + (((2+rtl)*64 + lg20*16+col)<<4) + rp*4);
        fC1 += *(const float*)(db + (((2+rtl)*64 + lg21*16+col)<<4) + rp*4);
      }
      float bfc=BIAS[col], bcc=BIAS[16+col];
      float preF0=fminf(fmaxf(fF0+bfc,-30.f),30.f);
      float preC0=fminf(fmaxf(fC0+bcc,-30.f),30.f);
      float preF1=fminf(fmaxf(fF1+bfc,-30.f),30.f);
      float preC1=fminf(fmaxf(fC1+bcc,-30.f),30.f);
      float fg0=1.f/(1.f+__expf(-preF0)), e0=__expf(-2.f*preC0);
      float cd0=(1.f-e0)/(1.f+e0);
      float fg1=1.f/(1.f+__expf(-preF1)), e1=__expf(-2.f*preC1);
      float cd1=(1.f-e1)/(1.f+e1);
      float ns0=fg0*sreg.x+(1.f-fg0)*cd0;
      float ns1=fg1*sreg.y+(1.f-fg1)*cd1;
      sreg.x=ns0; sreg.y=ns1;
      if (li==3){ pns.x=ns0; pns.y=ns1; }
      NSf[r0*NSTR+col]=ns0;
      NSf[r1*NSTR+col]=ns1;
    }
    BARS;

    if (lane<16){
      int row = v*8 + (lane>>1), hf = lane&1;
      const float* nr = NSf + row*NSTR + hf*8;
      f32x4 q0 = *(const f32x4*)nr, q1 = *(const f32x4*)(nr+4);
      unsigned w0=pk2h(q0[0],q0[1]), w1=pk2h(q0[2],q0[3]);
      unsigned w2=pk2h(q1[0],q1[1]), w3=pk2h(q1[2],q1[3]);
      unsigned short* sd = H16 + ((size_t)li*513 + (size_t)(t+1))*32768 + row*1024 + wr*16 + hf*8;
      cstore16(sd, w0, w1, w2, w3);
      if (t==T_-1){
        float* op = ostate + (size_t)li*BD_ + (size_t)row*D_ + wr*16 + hf*8;
        *(f32x4*)op = q0; *(f32x4*)(op+4) = q1;
      }
    }

    // ---- arrive
    asm volatile("s_waitcnt vmcnt(0)" ::: "memory");
    __syncthreads();
    if (tid==0)
      __hip_atomic_fetch_add(prog+li*64, 1u, __ATOMIC_RELAXED, __HIP_MEMORY_SCOPE_AGENT);
  }

  // ---- tail: y[511] — load ns(511) tile (slot 512), reduce stats, write
  if (li==3){
    if (tid==0){
      while (cldu(prog+3*64) < 64u*(unsigned)T_) __builtin_amdgcn_s_sleep(1);
    }
    __syncthreads();
    u64 sbS = (u64)(uintptr_t)(H16 + ((size_t)3*513 + (size_t)T_)*32768);
    u32x4 pS[16];
    GLDX(pS[0],  voA+0*256, sbS); GLDX(pS[1],  voB+0*256, sbS);
    GLDX(pS[2],  voA+1*256, sbS); GLDX(pS[3],  voB+1*256, sbS);
    GLDX(pS[4],  voA+2*256, sbS); GLDX(pS[5],  voB+2*256, sbS);
    GLDX(pS[6],  voA+3*256, sbS); GLDX(pS[7],  voB+3*256, sbS);
    GLDX(pS[8],  voA+4*256, sbS); GLDX(pS[9],  voB+4*256, sbS);
    GLDX(pS[10], voA+5*256, sbS); GLDX(pS[11], voB+5*256, sbS);
    GLDX(pS[12], voA+6*256, sbS); GLDX(pS[13], voB+6*256, sbS);
    GLDX(pS[14], voA+7*256, sbS); GLDX(pS[15], voB+7*256, sbS);
    WAITV(0);
    float sS=0.f,qS=0.f,sT=0.f,qT=0.f;
    #pragma unroll
    for (int c2=0;c2<8;++c2){
      f16x8 tA=__builtin_bit_cast(f16x8,pS[2*c2]);
      f16x8 tB=__builtin_bit_cast(f16x8,pS[2*c2+1]);
      #pragma unroll
      for (int j=0;j<8;++j){
        float fa=(float)tA[j], fb=(float)tB[j];
        sS+=fa; qS+=fa*fa; sT+=fb; qT+=fb*fb;
      }
    }
    sS+=__shfl_xor(sS,16); qS+=__shfl_xor(qS,16); sT+=__shfl_xor(sT,16); qT+=__shfl_xor(qT,16);
    sS+=__shfl_xor(sS,32); qS+=__shfl_xor(qS,32); sT+=__shfl_xor(sT,32); qT+=__shfl_xor(qT,32);
    if (lane<16){ f32x4 pk={sS,qS,sT,qT}; *(f32x4*)(RED1+((v*16+lane)<<4))=pk; }
    BARS;
    f32x4 sp0={0.f,0.f,0.f,0.f}, sp1={0.f,0.f,0.f,0.f};
    #pragma unroll
    for (int vv=0;vv<4;++vv){
      sp0 += *(const f32x4*)(RED1+((vv*16+(r0&15))<<4));
      sp1 += *(const f32x4*)(RED1+((vv*16+(r1&15))<<4));
    }
    float gv=SGSB[col], bv=SGSB[16+col];
    float s0=(r0<16)? sp0.x : sp0.z, q0=(r0<16)? sp0.y : sp0.w;
    float m0=s0*(1.f/1024.f);
    float rs0=rsqrtf(q0*(1.f/1024.f)-m0*m0+EPSF);
    y[(size_t)(T_-1)*BD_+(size_t)r0*D_+wr*16+col]=(pns.x-m0)*rs0*gv+bv;
    float s1v=(r1<16)? sp1.x : sp1.z, q1v=(r1<16)? sp1.y : sp1.w;
    float m1=s1v*(1.f/1024.f);
    float rs1=rsqrtf(q1v*(1.f/1024.f)-m1*m1+EPSF);
    y[(size_t)(T_-1)*BD_+(size_t)r1*D_+wr*16+col]=(pns.y-m1)*rs1*gv+bv;
  }
}

extern "C" void kernel_launch(void* const* d_in, const int* in_sizes, int n_in,
                              void* d_out, int out_size, void* d_ws, size_t ws_size,
                              hipStream_t stream){
  (void)in_sizes; (void)n_in; (void)out_size; (void)ws_size;
  const float* x   = (const float*)d_in[0];
  const float* st0 = (const float*)d_in[1];
  const float* Wf  = (const float*)d_in[2];
  const float* Uf  = (const float*)d_in[3];
  const float* bfv = (const float*)d_in[4];
  const float* Wc  = (const float*)d_in[5];
  const float* Uc  = (const float*)d_in[6];
  const float* bcv = (const float*)d_in[7];
  const float* pg  = (const float*)d_in[8];
  const float* pb  = (const float*)d_in[9];
  const float* sg  = (const float*)d_in[10];
  const float* sbv = (const float*)d_in[11];

  float* y      = (float*)d_out;
  float* ostate = y + (size_t)T_*BD_;
  char* ws = (char*)d_ws;

  (void)hipMemsetAsync(ws, 0, 4096, stream);
  hipLaunchKernelGGL(crs_prepass, dim3(8192), dim3(256), 0, stream,
                     Wf, Uf, Wc, Uc, (unsigned short*)(ws+WSO_WT));
  hipLaunchKernelGGL(crs_prep2, dim3(L_), dim3(256), 0, stream,
                     st0, (unsigned short*)(ws+WSO_H16));
  (void)hipFuncSetAttribute((const void*)crs_main, hipFuncAttributeMaxDynamicSharedMemorySize, LDS_TOTAL);
  hipLaunchKernelGGL(crs_main, dim3(NWG), dim3(TPB), LDS_TOTAL, stream,
                     x, st0, bfv, bcv, pg, pb, sg, sbv, y, ostate,
                     (const unsigned short*)(ws+WSO_WT), ws);
}